// Round 12
// baseline (114.272 us; speedup 1.0000x reference)
//
#include <hip/hip_runtime.h>
#include <math.h>

constexpr int NN = 32768;   // nodes
constexpr int SS = 32768;   // subgraph-node entries
constexpr int CC = 1024;    // clusters
constexpr int EE = 16384;   // coarsen edges
constexpr int BB = 16;      // graphs
constexpr int PP = 64;      // patches per graph
constexpr int NC = 10;      // classes

__device__ __forceinline__ float rdlane(float v, int l) {
    return __int_as_float(__builtin_amdgcn_readlane(__float_as_int(v), l));
}

// ---------------------------------------------------------------------------
// k_node: fused per-node dense chain + folded prep (deg, segoff, H/den zero).
// 3 GEMM passes (r10 shape): t1 = relu(x@W1+b1); h = relu(t1@W2+b2);
//                [u,K,V] = h@{Wp1,WK,WV} (triple-accumulator single A pass)
// ---------------------------------------------------------------------------
#define TS 68

__device__ __forceinline__ void gemm64(const float* A, const float* W,
                                       const float* __restrict__ bias,
                                       int r0, int c0, float acc[4][4])
{
#pragma unroll
    for (int dc = 0; dc < 4; ++dc) {
        float bv = bias[c0 + dc];
        acc[0][dc] = bv; acc[1][dc] = bv; acc[2][dc] = bv; acc[3][dc] = bv;
    }
#pragma unroll 16
    for (int k = 0; k < 64; ++k) {
        float4 av = *(const float4*)(A + k * TS + r0);
        float4 wv = *(const float4*)(W + k * TS + c0);
        acc[0][0] = fmaf(av.x, wv.x, acc[0][0]); acc[0][1] = fmaf(av.x, wv.y, acc[0][1]);
        acc[0][2] = fmaf(av.x, wv.z, acc[0][2]); acc[0][3] = fmaf(av.x, wv.w, acc[0][3]);
        acc[1][0] = fmaf(av.y, wv.x, acc[1][0]); acc[1][1] = fmaf(av.y, wv.y, acc[1][1]);
        acc[1][2] = fmaf(av.y, wv.z, acc[1][2]); acc[1][3] = fmaf(av.y, wv.w, acc[1][3]);
        acc[2][0] = fmaf(av.z, wv.x, acc[2][0]); acc[2][1] = fmaf(av.z, wv.y, acc[2][1]);
        acc[2][2] = fmaf(av.z, wv.z, acc[2][2]); acc[2][3] = fmaf(av.z, wv.w, acc[2][3]);
        acc[3][0] = fmaf(av.w, wv.x, acc[3][0]); acc[3][1] = fmaf(av.w, wv.y, acc[3][1]);
        acc[3][2] = fmaf(av.w, wv.z, acc[3][2]); acc[3][3] = fmaf(av.w, wv.w, acc[3][3]);
    }
}

__device__ __forceinline__ void gemm64x3(const float* A, const float* Wa,
                                         const float* Wb, const float* Wc_,
                                         const float* __restrict__ b1_,
                                         const float* __restrict__ b2_,
                                         const float* __restrict__ b3_,
                                         int r0, int c0,
                                         float a1_[4][4], float a2_[4][4], float a3_[4][4])
{
#pragma unroll
    for (int dc = 0; dc < 4; ++dc) {
        float v1 = b1_[c0 + dc], v2 = b2_[c0 + dc], v3 = b3_[c0 + dc];
#pragma unroll
        for (int dr = 0; dr < 4; ++dr) { a1_[dr][dc] = v1; a2_[dr][dc] = v2; a3_[dr][dc] = v3; }
    }
#pragma unroll 4
    for (int k = 0; k < 64; ++k) {
        float4 av = *(const float4*)(A + k * TS + r0);
        float4 w1 = *(const float4*)(Wa + k * TS + c0);
        float4 w2 = *(const float4*)(Wb + k * TS + c0);
        float4 w3 = *(const float4*)(Wc_ + k * TS + c0);
        float ar[4] = {av.x, av.y, av.z, av.w};
        float u1[4] = {w1.x, w1.y, w1.z, w1.w};
        float u2[4] = {w2.x, w2.y, w2.z, w2.w};
        float u3[4] = {w3.x, w3.y, w3.z, w3.w};
#pragma unroll
        for (int dr = 0; dr < 4; ++dr)
#pragma unroll
            for (int dc = 0; dc < 4; ++dc) {
                a1_[dr][dc] = fmaf(ar[dr], u1[dc], a1_[dr][dc]);
                a2_[dr][dc] = fmaf(ar[dr], u2[dc], a2_[dr][dc]);
                a3_[dr][dc] = fmaf(ar[dr], u3[dc], a3_[dr][dc]);
            }
    }
}

__device__ __forceinline__ void writeW(float* dst, int tid,
                                       float4 a, float4 b, float4 c, float4 d)
{
    int colq = (tid & 15) * 4;
    int rb = tid >> 4;
    *(float4*)(dst + (rb     ) * TS + colq) = a;
    *(float4*)(dst + (rb + 16) * TS + colq) = b;
    *(float4*)(dst + (rb + 32) * TS + colq) = c;
    *(float4*)(dst + (rb + 48) * TS + colq) = d;
}

__device__ __forceinline__ void writeXT(float* dst, int tid,
                                        float4 a, float4 b, float4 c, float4 d)
{
    int rb = (tid * 4) & 63;
    int cb = tid >> 4;
    dst[(rb + 0) * TS + cb     ] = a.x;
    dst[(rb + 1) * TS + cb     ] = a.y;
    dst[(rb + 2) * TS + cb     ] = a.z;
    dst[(rb + 3) * TS + cb     ] = a.w;
    dst[(rb + 0) * TS + cb + 16] = b.x;
    dst[(rb + 1) * TS + cb + 16] = b.y;
    dst[(rb + 2) * TS + cb + 16] = b.z;
    dst[(rb + 3) * TS + cb + 16] = b.w;
    dst[(rb + 0) * TS + cb + 32] = c.x;
    dst[(rb + 1) * TS + cb + 32] = c.y;
    dst[(rb + 2) * TS + cb + 32] = c.z;
    dst[(rb + 3) * TS + cb + 32] = c.w;
    dst[(rb + 0) * TS + cb + 48] = d.x;
    dst[(rb + 1) * TS + cb + 48] = d.y;
    dst[(rb + 2) * TS + cb + 48] = d.z;
    dst[(rb + 3) * TS + cb + 48] = d.w;
}

__device__ __forceinline__ void outT_relu(float* dst, int r0, int c0, float acc[4][4])
{
#pragma unroll
    for (int dc = 0; dc < 4; ++dc) {
        *(float4*)(dst + (c0 + dc) * TS + r0) =
            make_float4(fmaxf(acc[0][dc], 0.f), fmaxf(acc[1][dc], 0.f),
                        fmaxf(acc[2][dc], 0.f), fmaxf(acc[3][dc], 0.f));
    }
}

__device__ __forceinline__ void outG2(float* __restrict__ dst, size_t rowbase, int ld,
                                      int off, int r0, int c0, float acc[4][4], bool dorelu)
{
#pragma unroll
    for (int dr = 0; dr < 4; ++dr) {
        float4 v = make_float4(acc[dr][0], acc[dr][1], acc[dr][2], acc[dr][3]);
        if (dorelu) {
            v.x = fmaxf(v.x, 0.f); v.y = fmaxf(v.y, 0.f);
            v.z = fmaxf(v.z, 0.f); v.w = fmaxf(v.w, 0.f);
        }
        *(float4*)(dst + (rowbase + r0 + dr) * ld + off + c0) = v;
    }
}

__global__ __launch_bounds__(256, 2) void k_node(
    const float* __restrict__ x,
    const int* __restrict__ row, const float* __restrict__ attr,
    const int* __restrict__ batch,
    const float* __restrict__ W1, const float* __restrict__ b1,
    const float* __restrict__ W2, const float* __restrict__ b2,
    const float* __restrict__ Wp1, const float* __restrict__ bp1,
    const float* __restrict__ WK, const float* __restrict__ bK,
    const float* __restrict__ WV, const float* __restrict__ bV,
    float* __restrict__ u, float* __restrict__ KV,
    float* __restrict__ deg, int* __restrict__ segoff, float* __restrict__ zbase)
{
    __shared__ __align__(16) float bufA[64 * TS];
    __shared__ __align__(16) float bufB[64 * TS];
    __shared__ __align__(16) float w0[64 * TS];
    __shared__ __align__(16) float w1[64 * TS];
    __shared__ float ldeg[16];
    int tid = threadIdx.x;
    int b = blockIdx.x;
    if (tid < 33) {
        int i = b * 33 + tid;
        if (i < 16640) ((float4*)zbase)[i] = make_float4(0.f, 0.f, 0.f, 0.f);
    }
    if (b < 64) {
        if (tid < 16) ldeg[tid] = 0.f;
        __syncthreads();
        int lo = b * 16;
#pragma unroll 4
        for (int i = 0; i < 64; ++i) {
            int e = i * 256 + tid;
            int r = row[e];
            unsigned d = (unsigned)(r - lo);
            if (d < 16u) atomicAdd(&ldeg[d], attr[e]);
        }
        __syncthreads();
        if (tid < 16) deg[lo + tid] = ldeg[tid];
    } else if (b < 192) {
        int t = (b - 64) * 256 + tid;
        int cur = batch[t];
        int prev = (t == 0) ? -1 : batch[t - 1];
        for (int c = prev + 1; c <= cur; ++c) segoff[c] = t;
        if (t == SS - 1)
            for (int c = cur + 1; c <= CC; ++c) segoff[c] = SS;
    }
    int tx = tid & 15, ty = tid >> 4;
    int r0 = ty * 4, c0 = tx * 4;
    size_t rowbase = (size_t)b * 64;
    const float* xb = x + rowbase * 64;
    float4 a0 = ((const float4*)W1)[tid];
    float4 a1 = ((const float4*)W1)[tid + 256];
    float4 a2 = ((const float4*)W1)[tid + 512];
    float4 a3 = ((const float4*)W1)[tid + 768];
    float4 x0 = ((const float4*)xb)[tid];
    float4 x1 = ((const float4*)xb)[tid + 256];
    float4 x2 = ((const float4*)xb)[tid + 512];
    float4 x3 = ((const float4*)xb)[tid + 768];
    writeW(w0, tid, a0, a1, a2, a3);
    writeXT(bufA, tid, x0, x1, x2, x3);
    __syncthreads();
    float acc[4][4];
    // P0: t1 = relu(x@W1+b1) -> bufB ; prefetch W2
    a0 = ((const float4*)W2)[tid];
    a1 = ((const float4*)W2)[tid + 256];
    a2 = ((const float4*)W2)[tid + 512];
    a3 = ((const float4*)W2)[tid + 768];
    gemm64(bufA, w0, b1, r0, c0, acc);
    outT_relu(bufB, r0, c0, acc);
    writeW(w1, tid, a0, a1, a2, a3);
    __syncthreads();
    // P1: h = relu(t1@W2+b2) -> bufA ; prefetch Wp1, WK, WV
    a0 = ((const float4*)Wp1)[tid];
    a1 = ((const float4*)Wp1)[tid + 256];
    a2 = ((const float4*)Wp1)[tid + 512];
    a3 = ((const float4*)Wp1)[tid + 768];
    float4 k0 = ((const float4*)WK)[tid];
    float4 k1 = ((const float4*)WK)[tid + 256];
    float4 k2 = ((const float4*)WK)[tid + 512];
    float4 k3 = ((const float4*)WK)[tid + 768];
    float4 v0 = ((const float4*)WV)[tid];
    float4 v1 = ((const float4*)WV)[tid + 256];
    float4 v2 = ((const float4*)WV)[tid + 512];
    float4 v3 = ((const float4*)WV)[tid + 768];
    gemm64(bufB, w1, b2, r0, c0, acc);
    outT_relu(bufA, r0, c0, acc);
    writeW(w0, tid, a0, a1, a2, a3);   // Wp1
    writeW(w1, tid, k0, k1, k2, k3);   // WK
    writeW(bufB, tid, v0, v1, v2, v3); // WV into dead bufB
    __syncthreads();
    // P2: u = relu(h@Wp1+bp1), K = h@WK+bK, V = h@WV+bV (single A pass)
    float accU[4][4], accK[4][4], accV[4][4];
    gemm64x3(bufA, w0, w1, bufB, bp1, bK, bV, r0, c0, accU, accK, accV);
    outG2(u, rowbase, 64, 0, r0, c0, accU, true);
    outG2(KV, rowbase, 128, 0, r0, c0, accK, false);
    outG2(KV, rowbase, 128, 64, r0, c0, accV, false);
}

// ---------------------------------------------------------------------------
// k_qk: per-cluster Q path: Qs=(sum u[mapper])@Wp2 + L*bp2;
//       Qk = relu(relu(Qs@Wpo1+bpo1)@Wpo2+bpo2).
// ---------------------------------------------------------------------------
__global__ __launch_bounds__(256, 4) void k_qk(
    const float* __restrict__ u, const int* __restrict__ mapper,
    const int* __restrict__ segoff,
    const float* __restrict__ Wp2, const float* __restrict__ bp2,
    const float* __restrict__ Wpo1, const float* __restrict__ bpo1,
    const float* __restrict__ Wpo2, const float* __restrict__ bpo2,
    float* __restrict__ Qk)
{
    __shared__ float accs[4][64];
    int c = blockIdx.x;
    int tid = threadIdx.x, j = tid & 63, g = tid >> 6;
    int s0 = segoff[c], s1 = segoff[c + 1];
    float L = (float)(s1 - s0);
    if (tid < 64) {
        accs[0][tid] = 0.f;
        accs[1][tid] = L * bp2[tid];
        accs[2][tid] = bpo1[tid];
        accs[3][tid] = bpo2[tid];
    }
    __syncthreads();
    float us = 0.f;
    for (int s = s0 + g; s < s1; s += 4) us += u[(size_t)mapper[s] * 64 + j];
    atomicAdd(&accs[0][j], us);
    __syncthreads();
    float usv = accs[0][j];
    float p = 0.f;
#pragma unroll
    for (int t = 0; t < 16; ++t) {
        int i = g * 16 + t;
        p = fmaf(rdlane(usv, i), Wp2[i * 64 + j], p);
    }
    atomicAdd(&accs[1][j], p);
    __syncthreads();
    float qs = accs[1][j];
    p = 0.f;
#pragma unroll
    for (int t = 0; t < 16; ++t) {
        int i = g * 16 + t;
        p = fmaf(rdlane(qs, i), Wpo1[i * 64 + j], p);
    }
    atomicAdd(&accs[2][j], p);
    __syncthreads();
    float tv = fmaxf(accs[2][j], 0.f);
    p = 0.f;
#pragma unroll
    for (int t = 0; t < 16; ++t) {
        int i = g * 16 + t;
        p = fmaf(rdlane(tv, i), Wpo2[i * 64 + j], p);
    }
    atomicAdd(&accs[3][j], p);
    __syncthreads();
    if (g == 0) Qk[c * 64 + j] = fmaxf(accs[3][j], 0.f);
}

// ---------------------------------------------------------------------------
// k_msbedge: TWO blocks per cluster (half = K-feature rows 0-31 / 32-63).
// Each half builds its 32 rows of msb' = sb2*relu(K)^T@V + sa2*ksk⊗vsum in
// an LDS buffer that ALIASES the dead K/V staging space (~16KB total -> all
// 8 blocks/CU resident). Edge phase: wave-per-4-edges, lane j = V-col j,
// 32-deep readlane loop; H/den partial contributions via atomics (the two
// halves sum disjoint i-ranges).
// ---------------------------------------------------------------------------
#define KS 36   // Kr stride: 32 K-cols + 4 pad
#define VS 72   // Vb stride: 64 V-cols + 8 pad
#define MS 68   // msb stride

__global__ __launch_bounds__(256, 6) void k_msbedge(
    const float* __restrict__ KV, const int* __restrict__ mapper,
    const int* __restrict__ segoff, const float* __restrict__ Qk,
    const int* __restrict__ row, const int* __restrict__ col,
    const float* __restrict__ attr, const float* __restrict__ deg,
    const float* __restrict__ ab,
    float* __restrict__ H, float* __restrict__ den)
{
    __shared__ __align__(16) float pool[32 * KS + 32 * VS];  // Kr | Vb ; msb alias
    __shared__ int map_lds[32];
    __shared__ float ksum[32], krsl[32], vsum[64], dvec[32];
    __shared__ int eids[128];
    __shared__ int ecol[144];
    __shared__ float ewt[144];
    __shared__ int ecnt;
    float* Kr  = pool;                 // [32][KS]
    float* Vb  = pool + 32 * KS;       // [32][VS]
    float* msb = pool;                 // [32][MS], valid after build
    int bid = blockIdx.x;
    int c = bid >> 1, half = bid & 1;
    int tid = threadIdx.x, j = tid & 63, g = tid >> 6;
    int tr = tid >> 4, tc = tid & 15;
    int i0 = tr * 2, c0 = tc * 4;
    if (tid == 0) ecnt = 0;
    if (tid < 32) { ksum[tid] = 0.f; krsl[tid] = 0.f; }
    if (tid < 64) vsum[tid] = 0.f;
    __syncthreads();
    // edge scan (row[] is L2-hot: read by all blocks)
#pragma unroll 4
    for (int i = 0; i < 64; ++i) {
        int e = i * 256 + tid;
        if (row[e] == c) {
            int p = atomicAdd(&ecnt, 1);
            if (p < 128) eids[p] = e;
        }
    }
    __syncthreads();
    int ne = min(ecnt, 128);
    if (ne == 0) return;
    // build phase: chunks of 32 entries; this half stages K cols [32h,32h+32)
    int s0 = segoff[c], s1 = segoff[c + 1];
    int koff = half * 32;
    float acc[2][4] = {{0.f, 0.f, 0.f, 0.f}, {0.f, 0.f, 0.f, 0.f}};
    float ks = 0.f, krs = 0.f, vs = 0.f;
    for (int sb = s0; sb < s1; sb += 32) {
        int clen = min(32, s1 - sb);
        __syncthreads();
        if (tid < clen) map_lds[tid] = mapper[sb + tid];
        __syncthreads();
        for (int p = tid; p < clen * 8; p += 256) {
            int e = p >> 3, q = p & 7;
            *(float4*)(&Kr[e * KS + q * 4]) =
                *(const float4*)(KV + (size_t)map_lds[e] * 128 + koff + q * 4);
        }
        for (int p = tid; p < clen * 16; p += 256) {
            int e = p >> 4, q = p & 15;
            *(float4*)(&Vb[e * VS + q * 4]) =
                *(const float4*)(KV + (size_t)map_lds[e] * 128 + 64 + q * 4);
        }
        __syncthreads();
#pragma unroll 4
        for (int s = 0; s < clen; ++s) {
            float2 a2 = *(const float2*)(&Kr[s * KS + i0]);
            float4 b4 = *(const float4*)(&Vb[s * VS + c0]);
            float ar0 = fmaxf(a2.x, 0.f), ar1 = fmaxf(a2.y, 0.f);
            acc[0][0] = fmaf(ar0, b4.x, acc[0][0]); acc[0][1] = fmaf(ar0, b4.y, acc[0][1]);
            acc[0][2] = fmaf(ar0, b4.z, acc[0][2]); acc[0][3] = fmaf(ar0, b4.w, acc[0][3]);
            acc[1][0] = fmaf(ar1, b4.x, acc[1][0]); acc[1][1] = fmaf(ar1, b4.y, acc[1][1]);
            acc[1][2] = fmaf(ar1, b4.z, acc[1][2]); acc[1][3] = fmaf(ar1, b4.w, acc[1][3]);
        }
        for (int s = g; s < clen; s += 4) {
            if (j < 32) {
                float kv = Kr[s * KS + j];
                ks += kv;
                krs += fmaxf(kv, 0.f);
            }
            vs += Vb[s * VS + j];
        }
    }
    if (j < 32) { atomicAdd(&ksum[j], ks); atomicAdd(&krsl[j], krs); }
    atomicAdd(&vsum[j], vs);
    __syncthreads();   // sums complete; all Kr/Vb reads complete
    int L = s1 - s0;
    float Lr = (float)L;
    float invLm = 1.f / (float)(L > 0 ? L : 1);
    float a0 = ab[0], a1 = ab[1];
    float sa2 = 1.f + expf(a1 - a0);   // 1/softmax0
    float sb2 = 1.f + expf(a0 - a1);   // 1/softmax1
    float dr = deg[c];
    float dinvr = dr > 0.f ? 1.f / sqrtf(dr) : 0.f;
    // msb' into the alias region (+ rank-1 fold), dvec for den
    {
        float4 vsl4 = *(const float4*)(&vsum[c0]);
        float kk0 = fmaxf(ksum[i0] * invLm, 0.f) * sa2;
        float kk1 = fmaxf(ksum[i0 + 1] * invLm, 0.f) * sa2;
        *(float4*)(&msb[i0 * MS + c0]) =
            make_float4(fmaf(kk0, vsl4.x, sb2 * acc[0][0]),
                        fmaf(kk0, vsl4.y, sb2 * acc[0][1]),
                        fmaf(kk0, vsl4.z, sb2 * acc[0][2]),
                        fmaf(kk0, vsl4.w, sb2 * acc[0][3]));
        *(float4*)(&msb[(i0 + 1) * MS + c0]) =
            make_float4(fmaf(kk1, vsl4.x, sb2 * acc[1][0]),
                        fmaf(kk1, vsl4.y, sb2 * acc[1][1]),
                        fmaf(kk1, vsl4.z, sb2 * acc[1][2]),
                        fmaf(kk1, vsl4.w, sb2 * acc[1][3]));
    }
    if (tid < 32)
        dvec[tid] = sa2 * Lr * fmaxf(ksum[tid] * invLm, 0.f) + sb2 * krsl[tid];
    // edge metadata, padded to multiple of 16 with wt=0
    int nr = (ne + 15) & ~15;
    if (tid < ne) {
        int e = eids[tid];
        int cd = col[e];
        float dc = deg[cd];
        float dinvc = dc > 0.f ? 1.f / sqrtf(dc) : 0.f;
        ecol[tid] = cd;
        ewt[tid] = dinvr * attr[e] * dinvc;
    }
    for (int p = ne + tid; p < nr; p += 256) { ecol[p] = c; ewt[p] = 0.f; }
    __syncthreads();
    float dvj = (j < 32) ? dvec[j] : 0.f;
    int jq = half * 32 + (j & 31);
    // edge phase: wave g handles 4 edges per round, 32-deep readlane matvec
    for (int m0 = g * 4; m0 < nr; m0 += 16) {
        int cd0 = ecol[m0 + 0], cd1 = ecol[m0 + 1];
        int cd2 = ecol[m0 + 2], cd3 = ecol[m0 + 3];
        float wt0 = ewt[m0 + 0], wt1 = ewt[m0 + 1];
        float wt2 = ewt[m0 + 2], wt3 = ewt[m0 + 3];
        float q0 = Qk[(size_t)cd0 * 64 + jq];
        float q1 = Qk[(size_t)cd1 * 64 + jq];
        float q2 = Qk[(size_t)cd2 * 64 + jq];
        float q3 = Qk[(size_t)cd3 * 64 + jq];
        float o0 = 0.f, o1 = 0.f, o2 = 0.f, o3 = 0.f;
#pragma unroll
        for (int i = 0; i < 32; ++i) {
            float mv = msb[i * MS + j];
            o0 = fmaf(rdlane(q0, i), mv, o0);
            o1 = fmaf(rdlane(q1, i), mv, o1);
            o2 = fmaf(rdlane(q2, i), mv, o2);
            o3 = fmaf(rdlane(q3, i), mv, o3);
        }
        float p0 = q0 * dvj, p1 = q1 * dvj, p2 = q2 * dvj, p3 = q3 * dvj;
#pragma unroll
        for (int o = 32; o > 0; o >>= 1) {
            p0 += __shfl_xor(p0, o);
            p1 += __shfl_xor(p1, o);
            p2 += __shfl_xor(p2, o);
            p3 += __shfl_xor(p3, o);
        }
        atomicAdd(&H[(size_t)cd0 * 64 + j], wt0 * o0);
        atomicAdd(&H[(size_t)cd1 * 64 + j], wt1 * o1);
        atomicAdd(&H[(size_t)cd2 * 64 + j], wt2 * o2);
        atomicAdd(&H[(size_t)cd3 * 64 + j], wt3 * o3);
        if (j == 0) {
            atomicAdd(&den[cd0], wt0 * p0);
            atomicAdd(&den[cd1], wt1 * p1);
            atomicAdd(&den[cd2], wt2 * p2);
            atomicAdd(&den[cd3], wt3 * p3);
        }
    }
}

// ---------------------------------------------------------------------------
__global__ __launch_bounds__(64) void k_final(
    const float* __restrict__ H, const float* __restrict__ den,
    const float* __restrict__ Wc1, const float* __restrict__ bc1,
    const float* __restrict__ Wc2, const float* __restrict__ bc2,
    float* __restrict__ out)
{
    int bg = blockIdx.x;
    int j = threadIdx.x;
    float acc = 0.f;
    for (int p = 0; p < PP; ++p) {
        int c = bg * PP + p;
        acc += H[c * 64 + j] / (den[c] + 1e-6f);
    }
    float g = acc * (1.f / (float)PP);
    int m = j & 31;
    float a1 = bc1[m];
#pragma unroll
    for (int i = 0; i < 64; ++i) a1 = fmaf(rdlane(g, i), Wc1[i * 32 + m], a1);
    float c1 = fmaxf(a1, 0.f);
    int n = (j < NC) ? j : 0;
    float a2 = bc2[n];
#pragma unroll
    for (int i = 0; i < 32; ++i) a2 = fmaf(rdlane(c1, i), Wc2[i * NC + n], a2);
    if (j < NC) out[bg * NC + j] = a2;
}

// ---------------------------------------------------------------------------
extern "C" void kernel_launch(void* const* d_in, const int* in_sizes, int n_in,
                              void* d_out, int out_size, void* d_ws, size_t ws_size,
                              hipStream_t stream)
{
    const float* x      = (const float*)d_in[0];
    const int*   mapper = (const int*)d_in[1];
    const int*   batch  = (const int*)d_in[2];
    const int*   row    = (const int*)d_in[3];
    const int*   col    = (const int*)d_in[4];
    const float* attr   = (const float*)d_in[5];
    const float* W_in1  = (const float*)d_in[6];
    const float* b_in1  = (const float*)d_in[7];
    const float* W_in2  = (const float*)d_in[8];
    const float* b_in2  = (const float*)d_in[9];
    const float* W_pre1 = (const float*)d_in[10];
    const float* b_pre1 = (const float*)d_in[11];
    const float* W_pre2 = (const float*)d_in[12];
    const float* b_pre2 = (const float*)d_in[13];
    const float* W_post1= (const float*)d_in[14];
    const float* b_post1= (const float*)d_in[15];
    const float* W_post2= (const float*)d_in[16];
    const float* b_post2= (const float*)d_in[17];
    const float* W_K    = (const float*)d_in[18];
    const float* b_K    = (const float*)d_in[19];
    const float* W_V    = (const float*)d_in[20];
    const float* b_V    = (const float*)d_in[21];
    const float* alpha_beta = (const float*)d_in[22];
    const float* W_c1   = (const float*)d_in[23];
    const float* b_c1   = (const float*)d_in[24];
    const float* W_c2   = (const float*)d_in[25];
    const float* b_c2   = (const float*)d_in[26];

    float* ws = (float*)d_ws;
    float* u     = ws;                        // N*64
    float* KV    = u     + (size_t)NN * 64;   // N*128
    float* Qk    = KV    + (size_t)NN * 128;  // C*64
    float* deg   = Qk    + (size_t)CC * 64;   // C
    // --- zeroed by k_node: H (C*64) + den (C) ---
    float* H     = deg   + (size_t)CC;        // C*64
    float* den   = H     + (size_t)CC * 64;   // C
    int*  segoff = (int*)(den + (size_t)CC);  // C+1

    k_node<<<NN / 64, 256, 0, stream>>>(x, row, attr, batch,
                                        W_in1, b_in1, W_in2, b_in2,
                                        W_pre1, b_pre1, W_K, b_K, W_V, b_V,
                                        u, KV, deg, segoff, H);
    k_qk<<<CC, 256, 0, stream>>>(u, mapper, segoff, W_pre2, b_pre2,
                                 W_post1, b_post1, W_post2, b_post2, Qk);
    k_msbedge<<<2 * CC, 256, 0, stream>>>(KV, mapper, segoff, Qk, row, col,
                                          attr, deg, alpha_beta, H, den);
    k_final<<<BB, 64, 0, stream>>>(H, den, W_c1, b_c1, W_c2, b_c2, (float*)d_out);
}

// Round 13
// 89.940 us; speedup vs baseline: 1.2705x; 1.2705x over previous
//
#include <hip/hip_runtime.h>
#include <math.h>

constexpr int NN = 32768;   // nodes
constexpr int SS = 32768;   // subgraph-node entries
constexpr int CC = 1024;    // clusters
constexpr int EE = 16384;   // coarsen edges
constexpr int BB = 16;      // graphs
constexpr int PP = 64;      // patches per graph
constexpr int NC = 10;      // classes
constexpr int ECAP = 64;    // per-cluster edge bucket capacity (max deg ~38)

__device__ __forceinline__ float rdlane(float v, int l) {
    return __int_as_float(__builtin_amdgcn_readlane(__float_as_int(v), l));
}

// ---------------------------------------------------------------------------
// k_node: fused per-node dense chain + ALL prep folded in:
//   blocks 0..63   : deg[16b..16b+16) via LDS accumulate
//   blocks 64..191 : segoff boundary-writes over sorted batch
//   blocks 192..447: edge bucket fill — block owns 4 clusters, scans row[]
//                    once, LDS cursors, writes ebuck[c][..] + gcnt[c]
//   all blocks     : zero slice of H/den; 64-row tile of the dense chain
// 3 GEMM passes: t1=relu(x@W1+b1); h=relu(t1@W2+b2); [u,K,V]=h@{Wp1,WK,WV}
// ---------------------------------------------------------------------------
#define TS 68

__device__ __forceinline__ void gemm64(const float* A, const float* W,
                                       const float* __restrict__ bias,
                                       int r0, int c0, float acc[4][4])
{
#pragma unroll
    for (int dc = 0; dc < 4; ++dc) {
        float bv = bias[c0 + dc];
        acc[0][dc] = bv; acc[1][dc] = bv; acc[2][dc] = bv; acc[3][dc] = bv;
    }
#pragma unroll 16
    for (int k = 0; k < 64; ++k) {
        float4 av = *(const float4*)(A + k * TS + r0);
        float4 wv = *(const float4*)(W + k * TS + c0);
        acc[0][0] = fmaf(av.x, wv.x, acc[0][0]); acc[0][1] = fmaf(av.x, wv.y, acc[0][1]);
        acc[0][2] = fmaf(av.x, wv.z, acc[0][2]); acc[0][3] = fmaf(av.x, wv.w, acc[0][3]);
        acc[1][0] = fmaf(av.y, wv.x, acc[1][0]); acc[1][1] = fmaf(av.y, wv.y, acc[1][1]);
        acc[1][2] = fmaf(av.y, wv.z, acc[1][2]); acc[1][3] = fmaf(av.y, wv.w, acc[1][3]);
        acc[2][0] = fmaf(av.z, wv.x, acc[2][0]); acc[2][1] = fmaf(av.z, wv.y, acc[2][1]);
        acc[2][2] = fmaf(av.z, wv.z, acc[2][2]); acc[2][3] = fmaf(av.z, wv.w, acc[2][3]);
        acc[3][0] = fmaf(av.w, wv.x, acc[3][0]); acc[3][1] = fmaf(av.w, wv.y, acc[3][1]);
        acc[3][2] = fmaf(av.w, wv.z, acc[3][2]); acc[3][3] = fmaf(av.w, wv.w, acc[3][3]);
    }
}

__device__ __forceinline__ void gemm64x3(const float* A, const float* Wa,
                                         const float* Wb, const float* Wc_,
                                         const float* __restrict__ b1_,
                                         const float* __restrict__ b2_,
                                         const float* __restrict__ b3_,
                                         int r0, int c0,
                                         float a1_[4][4], float a2_[4][4], float a3_[4][4])
{
#pragma unroll
    for (int dc = 0; dc < 4; ++dc) {
        float v1 = b1_[c0 + dc], v2 = b2_[c0 + dc], v3 = b3_[c0 + dc];
#pragma unroll
        for (int dr = 0; dr < 4; ++dr) { a1_[dr][dc] = v1; a2_[dr][dc] = v2; a3_[dr][dc] = v3; }
    }
#pragma unroll 4
    for (int k = 0; k < 64; ++k) {
        float4 av = *(const float4*)(A + k * TS + r0);
        float4 w1 = *(const float4*)(Wa + k * TS + c0);
        float4 w2 = *(const float4*)(Wb + k * TS + c0);
        float4 w3 = *(const float4*)(Wc_ + k * TS + c0);
        float ar[4] = {av.x, av.y, av.z, av.w};
        float u1[4] = {w1.x, w1.y, w1.z, w1.w};
        float u2[4] = {w2.x, w2.y, w2.z, w2.w};
        float u3[4] = {w3.x, w3.y, w3.z, w3.w};
#pragma unroll
        for (int dr = 0; dr < 4; ++dr)
#pragma unroll
            for (int dc = 0; dc < 4; ++dc) {
                a1_[dr][dc] = fmaf(ar[dr], u1[dc], a1_[dr][dc]);
                a2_[dr][dc] = fmaf(ar[dr], u2[dc], a2_[dr][dc]);
                a3_[dr][dc] = fmaf(ar[dr], u3[dc], a3_[dr][dc]);
            }
    }
}

__device__ __forceinline__ void writeW(float* dst, int tid,
                                       float4 a, float4 b, float4 c, float4 d)
{
    int colq = (tid & 15) * 4;
    int rb = tid >> 4;
    *(float4*)(dst + (rb     ) * TS + colq) = a;
    *(float4*)(dst + (rb + 16) * TS + colq) = b;
    *(float4*)(dst + (rb + 32) * TS + colq) = c;
    *(float4*)(dst + (rb + 48) * TS + colq) = d;
}

__device__ __forceinline__ void writeXT(float* dst, int tid,
                                        float4 a, float4 b, float4 c, float4 d)
{
    int rb = (tid * 4) & 63;
    int cb = tid >> 4;
    dst[(rb + 0) * TS + cb     ] = a.x;
    dst[(rb + 1) * TS + cb     ] = a.y;
    dst[(rb + 2) * TS + cb     ] = a.z;
    dst[(rb + 3) * TS + cb     ] = a.w;
    dst[(rb + 0) * TS + cb + 16] = b.x;
    dst[(rb + 1) * TS + cb + 16] = b.y;
    dst[(rb + 2) * TS + cb + 16] = b.z;
    dst[(rb + 3) * TS + cb + 16] = b.w;
    dst[(rb + 0) * TS + cb + 32] = c.x;
    dst[(rb + 1) * TS + cb + 32] = c.y;
    dst[(rb + 2) * TS + cb + 32] = c.z;
    dst[(rb + 3) * TS + cb + 32] = c.w;
    dst[(rb + 0) * TS + cb + 48] = d.x;
    dst[(rb + 1) * TS + cb + 48] = d.y;
    dst[(rb + 2) * TS + cb + 48] = d.z;
    dst[(rb + 3) * TS + cb + 48] = d.w;
}

__device__ __forceinline__ void outT_relu(float* dst, int r0, int c0, float acc[4][4])
{
#pragma unroll
    for (int dc = 0; dc < 4; ++dc) {
        *(float4*)(dst + (c0 + dc) * TS + r0) =
            make_float4(fmaxf(acc[0][dc], 0.f), fmaxf(acc[1][dc], 0.f),
                        fmaxf(acc[2][dc], 0.f), fmaxf(acc[3][dc], 0.f));
    }
}

__device__ __forceinline__ void outG2(float* __restrict__ dst, size_t rowbase, int ld,
                                      int off, int r0, int c0, float acc[4][4], bool dorelu)
{
#pragma unroll
    for (int dr = 0; dr < 4; ++dr) {
        float4 v = make_float4(acc[dr][0], acc[dr][1], acc[dr][2], acc[dr][3]);
        if (dorelu) {
            v.x = fmaxf(v.x, 0.f); v.y = fmaxf(v.y, 0.f);
            v.z = fmaxf(v.z, 0.f); v.w = fmaxf(v.w, 0.f);
        }
        *(float4*)(dst + (rowbase + r0 + dr) * ld + off + c0) = v;
    }
}

__global__ __launch_bounds__(256, 2) void k_node(
    const float* __restrict__ x,
    const int* __restrict__ row, const float* __restrict__ attr,
    const int* __restrict__ batch,
    const float* __restrict__ W1, const float* __restrict__ b1,
    const float* __restrict__ W2, const float* __restrict__ b2,
    const float* __restrict__ Wp1, const float* __restrict__ bp1,
    const float* __restrict__ WK, const float* __restrict__ bK,
    const float* __restrict__ WV, const float* __restrict__ bV,
    float* __restrict__ u, float* __restrict__ KV,
    float* __restrict__ deg, int* __restrict__ segoff,
    int* __restrict__ gcnt, int* __restrict__ ebuck,
    float* __restrict__ zbase)
{
    __shared__ __align__(16) float bufA[64 * TS];
    __shared__ __align__(16) float bufB[64 * TS];
    __shared__ __align__(16) float w0[64 * TS];
    __shared__ __align__(16) float w1[64 * TS];
    __shared__ float ldeg[16];
    __shared__ int lbk[4];
    int tid = threadIdx.x;
    int b = blockIdx.x;
    // zero H/den (16640 float4 over 512 blocks)
    if (tid < 33) {
        int i = b * 33 + tid;
        if (i < 16640) ((float4*)zbase)[i] = make_float4(0.f, 0.f, 0.f, 0.f);
    }
    // folded prep
    if (b < 64) {
        if (tid < 16) ldeg[tid] = 0.f;
        __syncthreads();
        int lo = b * 16;
#pragma unroll 4
        for (int i = 0; i < 64; ++i) {
            int e = i * 256 + tid;
            int r = row[e];
            unsigned d = (unsigned)(r - lo);
            if (d < 16u) atomicAdd(&ldeg[d], attr[e]);
        }
        __syncthreads();
        if (tid < 16) deg[lo + tid] = ldeg[tid];
    } else if (b < 192) {
        int t = (b - 64) * 256 + tid;
        int cur = batch[t];
        int prev = (t == 0) ? -1 : batch[t - 1];
        for (int c = prev + 1; c <= cur; ++c) segoff[c] = t;
        if (t == SS - 1)
            for (int c = cur + 1; c <= CC; ++c) segoff[c] = SS;
    } else if (b < 448) {
        // edge bucket fill for 4 owned clusters
        int crow = (b - 192) * 4;
        if (tid < 4) lbk[tid] = 0;
        __syncthreads();
#pragma unroll 4
        for (int i = 0; i < 64; ++i) {
            int e = i * 256 + tid;
            int r = row[e];
            unsigned d = (unsigned)(r - crow);
            if (d < 4u) {
                int pos = atomicAdd(&lbk[d], 1);
                if (pos < ECAP) ebuck[(size_t)(crow + d) * ECAP + pos] = e;
            }
        }
        __syncthreads();
        if (tid < 4) gcnt[crow + tid] = min(lbk[tid], ECAP);
    }
    // dense chain
    int tx = tid & 15, ty = tid >> 4;
    int r0 = ty * 4, c0 = tx * 4;
    size_t rowbase = (size_t)b * 64;
    const float* xb = x + rowbase * 64;
    float4 a0 = ((const float4*)W1)[tid];
    float4 a1 = ((const float4*)W1)[tid + 256];
    float4 a2 = ((const float4*)W1)[tid + 512];
    float4 a3 = ((const float4*)W1)[tid + 768];
    float4 x0 = ((const float4*)xb)[tid];
    float4 x1 = ((const float4*)xb)[tid + 256];
    float4 x2 = ((const float4*)xb)[tid + 512];
    float4 x3 = ((const float4*)xb)[tid + 768];
    writeW(w0, tid, a0, a1, a2, a3);
    writeXT(bufA, tid, x0, x1, x2, x3);
    __syncthreads();
    float acc[4][4];
    // P0: t1 = relu(x@W1+b1) -> bufB ; prefetch W2
    a0 = ((const float4*)W2)[tid];
    a1 = ((const float4*)W2)[tid + 256];
    a2 = ((const float4*)W2)[tid + 512];
    a3 = ((const float4*)W2)[tid + 768];
    gemm64(bufA, w0, b1, r0, c0, acc);
    outT_relu(bufB, r0, c0, acc);
    writeW(w1, tid, a0, a1, a2, a3);
    __syncthreads();
    // P1: h = relu(t1@W2+b2) -> bufA ; prefetch Wp1, WK, WV
    a0 = ((const float4*)Wp1)[tid];
    a1 = ((const float4*)Wp1)[tid + 256];
    a2 = ((const float4*)Wp1)[tid + 512];
    a3 = ((const float4*)Wp1)[tid + 768];
    float4 k0 = ((const float4*)WK)[tid];
    float4 k1 = ((const float4*)WK)[tid + 256];
    float4 k2 = ((const float4*)WK)[tid + 512];
    float4 k3 = ((const float4*)WK)[tid + 768];
    float4 v0 = ((const float4*)WV)[tid];
    float4 v1 = ((const float4*)WV)[tid + 256];
    float4 v2 = ((const float4*)WV)[tid + 512];
    float4 v3 = ((const float4*)WV)[tid + 768];
    gemm64(bufB, w1, b2, r0, c0, acc);
    outT_relu(bufA, r0, c0, acc);
    writeW(w0, tid, a0, a1, a2, a3);   // Wp1
    writeW(w1, tid, k0, k1, k2, k3);   // WK
    writeW(bufB, tid, v0, v1, v2, v3); // WV into dead bufB
    __syncthreads();
    // P2: u = relu(h@Wp1+bp1), K = h@WK+bK, V = h@WV+bV (single A pass)
    float accU[4][4], accK[4][4], accV[4][4];
    gemm64x3(bufA, w0, w1, bufB, bp1, bK, bV, r0, c0, accU, accK, accV);
    outG2(u, rowbase, 64, 0, r0, c0, accU, true);
    outG2(KV, rowbase, 128, 0, r0, c0, accK, false);
    outG2(KV, rowbase, 128, 64, r0, c0, accV, false);
}

// ---------------------------------------------------------------------------
// k_qk: per-cluster Q path: Qs=(sum u[mapper])@Wp2 + L*bp2;
//       Qk = relu(relu(Qs@Wpo1+bpo1)@Wpo2+bpo2).
// ---------------------------------------------------------------------------
__global__ __launch_bounds__(256, 4) void k_qk(
    const float* __restrict__ u, const int* __restrict__ mapper,
    const int* __restrict__ segoff,
    const float* __restrict__ Wp2, const float* __restrict__ bp2,
    const float* __restrict__ Wpo1, const float* __restrict__ bpo1,
    const float* __restrict__ Wpo2, const float* __restrict__ bpo2,
    float* __restrict__ Qk)
{
    __shared__ float accs[4][64];
    int c = blockIdx.x;
    int tid = threadIdx.x, j = tid & 63, g = tid >> 6;
    int s0 = segoff[c], s1 = segoff[c + 1];
    float L = (float)(s1 - s0);
    if (tid < 64) {
        accs[0][tid] = 0.f;
        accs[1][tid] = L * bp2[tid];
        accs[2][tid] = bpo1[tid];
        accs[3][tid] = bpo2[tid];
    }
    __syncthreads();
    float us = 0.f;
    for (int s = s0 + g; s < s1; s += 4) us += u[(size_t)mapper[s] * 64 + j];
    atomicAdd(&accs[0][j], us);
    __syncthreads();
    float usv = accs[0][j];
    float p = 0.f;
#pragma unroll
    for (int t = 0; t < 16; ++t) {
        int i = g * 16 + t;
        p = fmaf(rdlane(usv, i), Wp2[i * 64 + j], p);
    }
    atomicAdd(&accs[1][j], p);
    __syncthreads();
    float qs = accs[1][j];
    p = 0.f;
#pragma unroll
    for (int t = 0; t < 16; ++t) {
        int i = g * 16 + t;
        p = fmaf(rdlane(qs, i), Wpo1[i * 64 + j], p);
    }
    atomicAdd(&accs[2][j], p);
    __syncthreads();
    float tv = fmaxf(accs[2][j], 0.f);
    p = 0.f;
#pragma unroll
    for (int t = 0; t < 16; ++t) {
        int i = g * 16 + t;
        p = fmaf(rdlane(tv, i), Wpo2[i * 64 + j], p);
    }
    atomicAdd(&accs[3][j], p);
    __syncthreads();
    if (g == 0) Qk[c * 64 + j] = fmaxf(accs[3][j], 0.f);
}

// ---------------------------------------------------------------------------
// k_msbedge: block per source cluster c. Edge list from precomputed bucket
// (no scan). Edge metadata computed up-front so gathers overlap the build.
// Build msb' = sb2*relu(K)^T@V + sa2*ksk⊗vsum in LDS; dvec for den.
// Edge phase: wave-per-edge, lane j = col j (contiguous atomics), 4 edges
// per wave per round.
// ---------------------------------------------------------------------------
#define KSTR 72
#define MSTR 68

__global__ __launch_bounds__(256, 4) void k_msbedge(
    const float* __restrict__ KV, const int* __restrict__ mapper,
    const int* __restrict__ segoff, const float* __restrict__ Qk,
    const int* __restrict__ col, const float* __restrict__ attr,
    const float* __restrict__ deg,
    const int* __restrict__ gcnt, const int* __restrict__ ebuck,
    const float* __restrict__ ab,
    float* __restrict__ H, float* __restrict__ den)
{
    __shared__ __align__(16) float Kr[32 * KSTR];
    __shared__ __align__(16) float Vb[32 * KSTR];
    __shared__ __align__(16) float msb[64 * MSTR];
    __shared__ int map_lds[32];
    __shared__ float sums[192];
    __shared__ float dvec[64];
    __shared__ int ecol[ECAP];
    __shared__ float ewt[ECAP];
    int c = blockIdx.x;
    int tid = threadIdx.x, j = tid & 63, g = tid >> 6;
    int tx = tid & 15, ty = tid >> 4;
    int r0 = ty * 4, c0 = tx * 4;
    int ne = gcnt[c];
    if (ne == 0) return;
    int nr = (ne + 15) & ~15;
    if (tid < 192) sums[tid] = 0.f;
    // edge metadata up-front (overlaps build latency)
    if (tid < ne) {
        int e = ebuck[(size_t)c * ECAP + tid];
        int cd = col[e];
        float dc = deg[cd];
        float dinvc = dc > 0.f ? 1.f / sqrtf(dc) : 0.f;
        float drr = deg[c];
        float dinvr = drr > 0.f ? 1.f / sqrtf(drr) : 0.f;
        ecol[tid] = cd;
        ewt[tid] = dinvr * attr[e] * dinvc;
    }
    for (int p = ne + tid; p < nr; p += 256) { ecol[p] = c; ewt[p] = 0.f; }
    // build phase: chunks of 32 entries
    int s0 = segoff[c], s1 = segoff[c + 1];
    float acc[4][4];
#pragma unroll
    for (int a = 0; a < 4; ++a)
#pragma unroll
        for (int bq = 0; bq < 4; ++bq) acc[a][bq] = 0.f;
    float ks = 0.f, krs = 0.f, vs = 0.f;
    for (int sb = s0; sb < s1; sb += 32) {
        int clen = min(32, s1 - sb);
        __syncthreads();
        if (tid < clen) map_lds[tid] = mapper[sb + tid];
        __syncthreads();
        for (int p = tid; p < clen * 32; p += 256) {
            int e = p >> 5, q = p & 31;
            int m = map_lds[e];
            float4 v = *(const float4*)(KV + (size_t)m * 128 + q * 4);
            float* dst = (q < 16) ? &Kr[e * KSTR + q * 4] : &Vb[e * KSTR + (q - 16) * 4];
            *(float4*)dst = v;
        }
        __syncthreads();
#pragma unroll 4
        for (int s = 0; s < clen; ++s) {
            float4 a4 = *(const float4*)(&Kr[s * KSTR + r0]);
            float4 b4 = *(const float4*)(&Vb[s * KSTR + c0]);
            float ar0 = fmaxf(a4.x, 0.f), ar1 = fmaxf(a4.y, 0.f);
            float ar2 = fmaxf(a4.z, 0.f), ar3 = fmaxf(a4.w, 0.f);
            acc[0][0] = fmaf(ar0, b4.x, acc[0][0]); acc[0][1] = fmaf(ar0, b4.y, acc[0][1]);
            acc[0][2] = fmaf(ar0, b4.z, acc[0][2]); acc[0][3] = fmaf(ar0, b4.w, acc[0][3]);
            acc[1][0] = fmaf(ar1, b4.x, acc[1][0]); acc[1][1] = fmaf(ar1, b4.y, acc[1][1]);
            acc[1][2] = fmaf(ar1, b4.z, acc[1][2]); acc[1][3] = fmaf(ar1, b4.w, acc[1][3]);
            acc[2][0] = fmaf(ar2, b4.x, acc[2][0]); acc[2][1] = fmaf(ar2, b4.y, acc[2][1]);
            acc[2][2] = fmaf(ar2, b4.z, acc[2][2]); acc[2][3] = fmaf(ar2, b4.w, acc[2][3]);
            acc[3][0] = fmaf(ar3, b4.x, acc[3][0]); acc[3][1] = fmaf(ar3, b4.y, acc[3][1]);
            acc[3][2] = fmaf(ar3, b4.z, acc[3][2]); acc[3][3] = fmaf(ar3, b4.w, acc[3][3]);
        }
        for (int s = g; s < clen; s += 4) {
            float kv = Kr[s * KSTR + j];
            ks += kv;
            krs += fmaxf(kv, 0.f);
            vs += Vb[s * KSTR + j];
        }
    }
    atomicAdd(&sums[j], ks);
    atomicAdd(&sums[64 + j], krs);
    atomicAdd(&sums[128 + j], vs);
    __syncthreads();
    int L = s1 - s0;
    float Lr = (float)L;
    float invLm = 1.f / (float)(L > 0 ? L : 1);
    float a0 = ab[0], a1 = ab[1];
    float sa2 = 1.f + expf(a1 - a0);   // 1/softmax0
    float sb2 = 1.f + expf(a0 - a1);   // 1/softmax1
    // dvec and transformed msb' (fold rank-1 term + sb2 scale)
    if (tid < 64) {
        float kskv = fmaxf(sums[tid] * invLm, 0.f);
        dvec[tid] = sa2 * Lr * kskv + sb2 * sums[64 + tid];
    }
    float4 vsl4 = *(const float4*)(&sums[128 + c0]);
#pragma unroll
    for (int a = 0; a < 4; ++a) {
        float kska = fmaxf(sums[r0 + a] * invLm, 0.f) * sa2;
        *(float4*)(&msb[(r0 + a) * MSTR + c0]) =
            make_float4(fmaf(kska, vsl4.x, sb2 * acc[a][0]),
                        fmaf(kska, vsl4.y, sb2 * acc[a][1]),
                        fmaf(kska, vsl4.z, sb2 * acc[a][2]),
                        fmaf(kska, vsl4.w, sb2 * acc[a][3]));
    }
    __syncthreads();
    float dvreg = dvec[j];
    // edge phase: wave g handles 4 edges per round
    for (int m0 = g * 4; m0 < nr; m0 += 16) {
        int cd0 = ecol[m0 + 0], cd1 = ecol[m0 + 1];
        int cd2 = ecol[m0 + 2], cd3 = ecol[m0 + 3];
        float wt0 = ewt[m0 + 0], wt1 = ewt[m0 + 1];
        float wt2 = ewt[m0 + 2], wt3 = ewt[m0 + 3];
        float q0 = Qk[(size_t)cd0 * 64 + j];
        float q1 = Qk[(size_t)cd1 * 64 + j];
        float q2 = Qk[(size_t)cd2 * 64 + j];
        float q3 = Qk[(size_t)cd3 * 64 + j];
        float o0 = 0.f, o1 = 0.f, o2 = 0.f, o3 = 0.f;
#pragma unroll
        for (int i = 0; i < 64; ++i) {
            float mv = msb[i * MSTR + j];
            o0 = fmaf(rdlane(q0, i), mv, o0);
            o1 = fmaf(rdlane(q1, i), mv, o1);
            o2 = fmaf(rdlane(q2, i), mv, o2);
            o3 = fmaf(rdlane(q3, i), mv, o3);
        }
        float p0 = q0 * dvreg, p1 = q1 * dvreg, p2 = q2 * dvreg, p3 = q3 * dvreg;
#pragma unroll
        for (int o = 32; o > 0; o >>= 1) {
            p0 += __shfl_xor(p0, o);
            p1 += __shfl_xor(p1, o);
            p2 += __shfl_xor(p2, o);
            p3 += __shfl_xor(p3, o);
        }
        atomicAdd(&H[(size_t)cd0 * 64 + j], wt0 * o0);
        atomicAdd(&H[(size_t)cd1 * 64 + j], wt1 * o1);
        atomicAdd(&H[(size_t)cd2 * 64 + j], wt2 * o2);
        atomicAdd(&H[(size_t)cd3 * 64 + j], wt3 * o3);
        if (j == 0) {
            atomicAdd(&den[cd0], wt0 * p0);
            atomicAdd(&den[cd1], wt1 * p1);
            atomicAdd(&den[cd2], wt2 * p2);
            atomicAdd(&den[cd3], wt3 * p3);
        }
    }
}

// ---------------------------------------------------------------------------
__global__ __launch_bounds__(64) void k_final(
    const float* __restrict__ H, const float* __restrict__ den,
    const float* __restrict__ Wc1, const float* __restrict__ bc1,
    const float* __restrict__ Wc2, const float* __restrict__ bc2,
    float* __restrict__ out)
{
    int bg = blockIdx.x;
    int j = threadIdx.x;
    float acc = 0.f;
    for (int p = 0; p < PP; ++p) {
        int c = bg * PP + p;
        acc += H[c * 64 + j] / (den[c] + 1e-6f);
    }
    float g = acc * (1.f / (float)PP);
    int m = j & 31;
    float a1 = bc1[m];
#pragma unroll
    for (int i = 0; i < 64; ++i) a1 = fmaf(rdlane(g, i), Wc1[i * 32 + m], a1);
    float c1 = fmaxf(a1, 0.f);
    int n = (j < NC) ? j : 0;
    float a2 = bc2[n];
#pragma unroll
    for (int i = 0; i < 32; ++i) a2 = fmaf(rdlane(c1, i), Wc2[i * NC + n], a2);
    if (j < NC) out[bg * NC + j] = a2;
}

// ---------------------------------------------------------------------------
extern "C" void kernel_launch(void* const* d_in, const int* in_sizes, int n_in,
                              void* d_out, int out_size, void* d_ws, size_t ws_size,
                              hipStream_t stream)
{
    const float* x      = (const float*)d_in[0];
    const int*   mapper = (const int*)d_in[1];
    const int*   batch  = (const int*)d_in[2];
    const int*   row    = (const int*)d_in[3];
    const int*   col    = (const int*)d_in[4];
    const float* attr   = (const float*)d_in[5];
    const float* W_in1  = (const float*)d_in[6];
    const float* b_in1  = (const float*)d_in[7];
    const float* W_in2  = (const float*)d_in[8];
    const float* b_in2  = (const float*)d_in[9];
    const float* W_pre1 = (const float*)d_in[10];
    const float* b_pre1 = (const float*)d_in[11];
    const float* W_pre2 = (const float*)d_in[12];
    const float* b_pre2 = (const float*)d_in[13];
    const float* W_post1= (const float*)d_in[14];
    const float* b_post1= (const float*)d_in[15];
    const float* W_post2= (const float*)d_in[16];
    const float* b_post2= (const float*)d_in[17];
    const float* W_K    = (const float*)d_in[18];
    const float* b_K    = (const float*)d_in[19];
    const float* W_V    = (const float*)d_in[20];
    const float* b_V    = (const float*)d_in[21];
    const float* alpha_beta = (const float*)d_in[22];
    const float* W_c1   = (const float*)d_in[23];
    const float* b_c1   = (const float*)d_in[24];
    const float* W_c2   = (const float*)d_in[25];
    const float* b_c2   = (const float*)d_in[26];

    float* ws = (float*)d_ws;
    float* u     = ws;                        // N*64
    float* KV    = u     + (size_t)NN * 64;   // N*128
    float* Qk    = KV    + (size_t)NN * 128;  // C*64
    float* deg   = Qk    + (size_t)CC * 64;   // C
    // --- zeroed by k_node: H (C*64) + den (C) ---
    float* H     = deg   + (size_t)CC;        // C*64
    float* den   = H     + (size_t)CC * 64;   // C
    int*  segoff = (int*)(den + (size_t)CC);  // C+1
    int*  gcnt   = segoff + (CC + 1);         // C
    int*  ebuck  = gcnt + CC;                 // C*ECAP

    k_node<<<NN / 64, 256, 0, stream>>>(x, row, attr, batch,
                                        W_in1, b_in1, W_in2, b_in2,
                                        W_pre1, b_pre1, W_K, b_K, W_V, b_V,
                                        u, KV, deg, segoff, gcnt, ebuck, H);
    k_qk<<<CC, 256, 0, stream>>>(u, mapper, segoff, W_pre2, b_pre2,
                                 W_post1, b_post1, W_post2, b_post2, Qk);
    k_msbedge<<<CC, 256, 0, stream>>>(KV, mapper, segoff, Qk, col, attr,
                                      deg, gcnt, ebuck, alpha_beta, H, den);
    k_final<<<BB, 64, 0, stream>>>(H, den, W_c1, b_c1, W_c2, b_c2, (float*)d_out);
}